// Round 1
// baseline (927.298 us; speedup 1.0000x reference)
//
#include <hip/hip_runtime.h>

// SepKANLayer1D: B=4, IN_C=8, OUT_C=8, N=65536, SIZE=640 (512 coef + 64 uw + 64 rw)
// x: (4, 8, 65536) f32; w: (4, 640, 65536) f32; out: (4, 8, 65536) f32
// Memory-bound: ~656 MB traffic, roofline ~104 us @ 6.3 TB/s.

constexpr int NTOK = 65536;      // tokens per batch (N)
constexpr int SIZE = 640;

__device__ __forceinline__ float silu_f(float v) {
    return v / (1.0f + __expf(-v));
}

// Cox-de Boor recursion, grid_size=5, order=3, uniform knots g[j]=0.2*(j-3), j=0..11.
// Matches the reference exactly (same comparisons, same left/right weights;
// division replaced by compile-time reciprocal constants, ~1ulp).
__device__ __forceinline__ void bspline8(float x, float bs[8]) {
    float b[11];
#pragma unroll
    for (int j = 0; j < 11; ++j) {
        float gj  = 0.2f * (float)(j - 3);
        float gj1 = 0.2f * (float)(j - 2);
        b[j] = (x >= gj && x < gj1) ? 1.0f : 0.0f;
    }
#pragma unroll
    for (int p = 1; p <= 3; ++p) {
#pragma unroll
        for (int j = 0; j <= 10 - p; ++j) {
            float gj   = 0.2f * (float)(j - 3);
            float gjp  = 0.2f * (float)(j + p - 3);
            float gj1  = 0.2f * (float)(j - 2);
            float gjp1 = 0.2f * (float)(j + p - 2);
            float left  = (x - gj)   * (1.0f / (gjp  - gj));   // consts folded
            float right = (gjp1 - x) * (1.0f / (gjp1 - gj1));  // consts folded
            b[j] = left * b[j] + right * b[j + 1];
        }
    }
#pragma unroll
    for (int k = 0; k < 8; ++k) bs[k] = b[k];
}

__global__ __launch_bounds__(256) void kan_kernel(
    const float* __restrict__ x, const float* __restrict__ w,
    float* __restrict__ out)
{
    int tid = blockIdx.x * blockDim.x + threadIdx.x;        // 0..65535
    long long tok = (long long)tid * 4;                     // first of 4 tokens
    int b = (int)(tok / NTOK);
    int n = (int)(tok % NTOK);                              // multiple of 4

    const float* xb = x + ((long long)b * 8) * NTOK + n;
    const float* wb = w + ((long long)b * SIZE) * NTOK + n;
    float*       ob = out + ((long long)b * 8) * NTOK + n;

    float4 y[8];
#pragma unroll
    for (int o = 0; o < 8; ++o) y[o] = make_float4(0.f, 0.f, 0.f, 0.f);

#pragma unroll 1   // keep i-loop rolled: body ~10KB fits I$
    for (int i = 0; i < 8; ++i) {
        float4 xv = *(const float4*)(xb + (long long)i * NTOK);

        float bs[4][8];
        bspline8(xv.x, bs[0]);
        bspline8(xv.y, bs[1]);
        bspline8(xv.z, bs[2]);
        bspline8(xv.w, bs[3]);

        float4 sil;
        sil.x = silu_f(xv.x); sil.y = silu_f(xv.y);
        sil.z = silu_f(xv.z); sil.w = silu_f(xv.w);

        const float* wc = wb + (long long)(i * 64) * NTOK;        // coef[i][o][k]
        const float* wu = wb + (long long)(512 + i * 8) * NTOK;   // uw[i][o]
        const float* wr = wb + (long long)(576 + i * 8) * NTOK;   // rw[i][o]

#pragma unroll
        for (int o = 0; o < 8; ++o) {
            float4 sp = make_float4(0.f, 0.f, 0.f, 0.f);
#pragma unroll
            for (int k = 0; k < 8; ++k) {
                float4 c = *(const float4*)(wc + (long long)(o * 8 + k) * NTOK);
                sp.x = fmaf(bs[0][k], c.x, sp.x);
                sp.y = fmaf(bs[1][k], c.y, sp.y);
                sp.z = fmaf(bs[2][k], c.z, sp.z);
                sp.w = fmaf(bs[3][k], c.w, sp.w);
            }
            float4 u = *(const float4*)(wu + (long long)o * NTOK);
            float4 r = *(const float4*)(wr + (long long)o * NTOK);
            y[o].x = fmaf(u.x, sp.x, fmaf(sil.x, r.x, y[o].x));
            y[o].y = fmaf(u.y, sp.y, fmaf(sil.y, r.y, y[o].y));
            y[o].z = fmaf(u.z, sp.z, fmaf(sil.z, r.z, y[o].z));
            y[o].w = fmaf(u.w, sp.w, fmaf(sil.w, r.w, y[o].w));
        }
    }

#pragma unroll
    for (int o = 0; o < 8; ++o)
        *(float4*)(ob + (long long)o * NTOK) = y[o];
}

extern "C" void kernel_launch(void* const* d_in, const int* in_sizes, int n_in,
                              void* d_out, int out_size, void* d_ws, size_t ws_size,
                              hipStream_t stream) {
    const float* x = (const float*)d_in[0];   // (4, 8, 65536)
    const float* w = (const float*)d_in[1];   // (4, 640, 65536)
    float* out = (float*)d_out;               // (4, 8, 65536)

    // 262144 tokens / 4 tokens-per-thread = 65536 threads
    dim3 block(256);
    dim3 grid(65536 / 256);
    kan_kernel<<<grid, block, 0, stream>>>(x, w, out);
}